// Round 1
// baseline (54.568 us; speedup 1.0000x reference)
//
#include <hip/hip_runtime.h>

// Problem constants (from reference): x (256,160,160) f32 -> out (256,320,640) f32
#define CH  256
#define H_  160
#define W0_ 160
#define RH  160   // res grid height
#define RW  320   // res grid width
#define OH  320
#define OW  640

#define TKR 16            // res rows per block
#define TKC 32            // res cols per block
#define LDS_H (TKR + 2)   // 18 (with halo)
#define LDS_W (TKC + 2)   // 34

__global__ __launch_bounds__(256)
void upsample_tsd_conv_kernel(const float* __restrict__ x, float* __restrict__ out) {
    __shared__ float L[LDS_H][LDS_W];

    const int c  = blockIdx.z;
    const int k0 = blockIdx.y * TKR;   // base res row
    const int j0 = blockIdx.x * TKC;   // base res col
    const float* __restrict__ xc = x + (size_t)c * (H_ * W0_);
    const int tid = threadIdx.x;

    // ---- Phase 1: compute res tile (with edge-clamped halo) into LDS ----
    // res(r,c):
    //   data site ((r+c) even): x[r, c>>1]
    //   hole: 0 if (c==319) or (r==159)  [those imply r even / c even resp.]
    //         else 0.25*(N+S+W+E) with reflect at borders (parity-preserving)
    for (int idx = tid; idx < LDS_H * LDS_W; idx += 256) {
        int rr = idx / LDS_W;
        int cc = idx - rr * LDS_W;
        int r  = k0 - 1 + rr;  r  = max(0, min(RH - 1, r));   // clamp halo -> edge
        int cl = j0 - 1 + cc;  cl = max(0, min(RW - 1, cl));  // (reproduces jax edge renorm)
        float v;
        if (((r ^ cl) & 1) == 0) {
            v = xc[r * W0_ + (cl >> 1)];
        } else if ((cl == RW - 1) || (r == RH - 1)) {
            v = 0.0f;   // unfilled holes stay zero
        } else {
            int rn = (r == 0) ? 1 : r - 1;   // reflect
            int rs = r + 1;                   // r < 159 in this branch
            int cw = (cl == 0) ? 1 : cl - 1;  // reflect
            int ce = cl + 1;                  // cl < 319 in this branch
            v = 0.25f * (xc[rn * W0_ + (cl >> 1)] + xc[rs * W0_ + (cl >> 1)] +
                         xc[r  * W0_ + (cw >> 1)] + xc[r  * W0_ + (ce >> 1)]);
        }
        L[rr][cc] = v;
    }
    __syncthreads();

    // ---- Phase 2: bilinear 2x upsample (weights .25/.75) + LR flip ----
    float* __restrict__ outc = out + (size_t)c * (OH * OW);
    #pragma unroll
    for (int i = 0; i < 2; ++i) {
        int ci = tid + i * 256;        // 0..511 res cells in the 16x32 tile
        int kr = ci >> 5;              // local res row 0..15
        int kc = ci & 31;              // local res col 0..31
        // LDS center = L[kr+1][kc+1]; need 3x3 neighborhood
        float a00 = L[kr    ][kc], a01 = L[kr    ][kc + 1], a02 = L[kr    ][kc + 2];
        float a10 = L[kr + 1][kc], a11 = L[kr + 1][kc + 1], a12 = L[kr + 1][kc + 2];
        float a20 = L[kr + 2][kc], a21 = L[kr + 2][kc + 1], a22 = L[kr + 2][kc + 2];
        // vertical blends: out row 2k uses rows (k-1,k) w (.25,.75); row 2k+1 uses (k,k+1) w (.75,.25)
        float v0l = 0.25f * a00 + 0.75f * a10;
        float v0c = 0.25f * a01 + 0.75f * a11;
        float v0r = 0.25f * a02 + 0.75f * a12;
        float v1l = 0.75f * a10 + 0.25f * a20;
        float v1c = 0.75f * a11 + 0.25f * a21;
        float v1r = 0.75f * a12 + 0.25f * a22;
        // horizontal blends -> pre-flip cols (2j, 2j+1)
        float o00 = 0.25f * v0l + 0.75f * v0c;   // col 2j,   row 2k
        float o01 = 0.75f * v0c + 0.25f * v0r;   // col 2j+1, row 2k
        float o10 = 0.25f * v1l + 0.75f * v1c;   // col 2j,   row 2k+1
        float o11 = 0.75f * v1c + 0.25f * v1r;   // col 2j+1, row 2k+1

        int k   = k0 + kr;
        int j   = j0 + kc;
        int oy  = 2 * k;
        int oxf = OW - 2 - 2 * j;      // flipped base col (even -> 8B aligned)
        // final[639-2j] = o00, final[638-2j] = o01  ->  float2{o01, o00} at oxf
        *reinterpret_cast<float2*>(&outc[(size_t)oy       * OW + oxf]) = make_float2(o01, o00);
        *reinterpret_cast<float2*>(&outc[(size_t)(oy + 1) * OW + oxf]) = make_float2(o11, o10);
    }
}

extern "C" void kernel_launch(void* const* d_in, const int* in_sizes, int n_in,
                              void* d_out, int out_size, void* d_ws, size_t ws_size,
                              hipStream_t stream) {
    (void)in_sizes; (void)n_in; (void)d_ws; (void)ws_size; (void)out_size;
    const float* x = (const float*)d_in[0];
    float* out = (float*)d_out;
    dim3 grid(RW / TKC, RH / TKR, CH);   // (10, 10, 256)
    dim3 block(256);
    upsample_tsd_conv_kernel<<<grid, block, 0, stream>>>(x, out);
}

// Round 3
// 52.722 us; speedup vs baseline: 1.0350x; 1.0350x over previous
//
#include <hip/hip_runtime.h>

// x (256,160,160) f32 -> out (256,320,640) f32
#define CH  256
#define H_  160
#define W0_ 160
#define RH  160   // res grid height
#define RW  320   // res grid width
#define OH  320
#define OW  640

#define TKR 32              // res rows per block
#define TKC 32              // res cols per block
#define LDS_H   (TKR + 2)   // 34
#define LDS_WU  (TKC + 2)   // 34 used cols
#define LDS_W   36          // padded (even -> 8B-aligned rows)

__global__ __launch_bounds__(256)
void upsample_tsd_conv_kernel(const float* __restrict__ x, float* __restrict__ out) {
    __shared__ float L[LDS_H][LDS_W];

    const int c  = blockIdx.z;
    const int k0 = blockIdx.y * TKR;   // base res row
    const int j0 = blockIdx.x * TKC;   // base res col
    const float* __restrict__ xc = x + (size_t)c * (H_ * W0_);
    const int tid = threadIdx.x;

    // ---- Phase 1: res tile + edge-clamped halo into LDS ----
    // res(r,c): data site ((r+c) even): x[r, c>>1]
    //           hole: 0 if (c==319 || r==159), else 0.25*(N+S+W+E) reflect
    for (int idx = tid; idx < LDS_H * LDS_WU; idx += 256) {
        int rr = idx / LDS_WU;
        int cc = idx - rr * LDS_WU;
        int r  = k0 - 1 + rr;  r  = max(0, min(RH - 1, r));   // clamp halo
        int cl = j0 - 1 + cc;  cl = max(0, min(RW - 1, cl));
        float v;
        if (((r ^ cl) & 1) == 0) {
            v = xc[r * W0_ + (cl >> 1)];
        } else if ((cl == RW - 1) || (r == RH - 1)) {
            v = 0.0f;
        } else {
            int rn = (r == 0) ? 1 : r - 1;
            int rs = r + 1;
            int cw = (cl == 0) ? 1 : cl - 1;
            int ce = cl + 1;
            v = 0.25f * (xc[rn * W0_ + (cl >> 1)] + xc[rs * W0_ + (cl >> 1)] +
                         xc[r  * W0_ + (cw >> 1)] + xc[r  * W0_ + (ce >> 1)]);
        }
        L[rr][cc] = v;
    }
    __syncthreads();

    // ---- Phase 2: bilinear 2x (.25/.75) + LR flip, float4 stores ----
    float* __restrict__ outc = out + (size_t)c * (OH * OW);
    #pragma unroll
    for (int t = 0; t < 2; ++t) {
        int p  = tid + t * 256;        // pair index 0..511
        int kr = p >> 4;               // local res row 0..31
        int kc = (p & 15) << 1;        // halo col base (even): pair = res cols jc, jc+1
        // 3 rows x 4 cols neighborhood as aligned float2 reads
        const float2 r0a = *reinterpret_cast<const float2*>(&L[kr    ][kc]);
        const float2 r0b = *reinterpret_cast<const float2*>(&L[kr    ][kc + 2]);
        const float2 r1a = *reinterpret_cast<const float2*>(&L[kr + 1][kc]);
        const float2 r1b = *reinterpret_cast<const float2*>(&L[kr + 1][kc + 2]);
        const float2 r2a = *reinterpret_cast<const float2*>(&L[kr + 2][kc]);
        const float2 r2b = *reinterpret_cast<const float2*>(&L[kr + 2][kc + 2]);
        // vertical blends per halo col kc..kc+3
        float v00 = 0.25f * r0a.x + 0.75f * r1a.x;
        float v01 = 0.25f * r0a.y + 0.75f * r1a.y;
        float v02 = 0.25f * r0b.x + 0.75f * r1b.x;
        float v03 = 0.25f * r0b.y + 0.75f * r1b.y;
        float v10 = 0.75f * r1a.x + 0.25f * r2a.x;
        float v11 = 0.75f * r1a.y + 0.25f * r2a.y;
        float v12 = 0.75f * r1b.x + 0.25f * r2b.x;
        float v13 = 0.75f * r1b.y + 0.25f * r2b.y;
        // horizontal blends -> pre-flip cols 2jc..2jc+3 (rows 2k, 2k+1)
        float p0 = 0.25f * v00 + 0.75f * v01;
        float p1 = 0.75f * v01 + 0.25f * v02;
        float p2 = 0.25f * v01 + 0.75f * v02;
        float p3 = 0.75f * v02 + 0.25f * v03;
        float q0 = 0.25f * v10 + 0.75f * v11;
        float q1 = 0.75f * v11 + 0.25f * v12;
        float q2 = 0.25f * v11 + 0.75f * v12;
        float q3 = 0.75f * v12 + 0.25f * v13;

        int k   = k0 + kr;
        int jc  = j0 + kc;             // res col of cell0 (even)
        int oy  = 2 * k;
        int oxf = OW - 4 - 2 * jc;     // flipped base col, 16B aligned
        // final[oxf+i] = pre[2jc+3-i]
        *reinterpret_cast<float4*>(&outc[(size_t)oy       * OW + oxf]) = make_float4(p3, p2, p1, p0);
        *reinterpret_cast<float4*>(&outc[(size_t)(oy + 1) * OW + oxf]) = make_float4(q3, q2, q1, q0);
    }
}

extern "C" void kernel_launch(void* const* d_in, const int* in_sizes, int n_in,
                              void* d_out, int out_size, void* d_ws, size_t ws_size,
                              hipStream_t stream) {
    (void)in_sizes; (void)n_in; (void)d_ws; (void)ws_size; (void)out_size;
    const float* x = (const float*)d_in[0];
    float* out = (float*)d_out;
    dim3 grid(RW / TKC, RH / TKR, CH);   // (10, 5, 256)
    dim3 block(256);
    upsample_tsd_conv_kernel<<<grid, block, 0, stream>>>(x, out);
}

// Round 4
// 50.882 us; speedup vs baseline: 1.0724x; 1.0362x over previous
//
#include <hip/hip_runtime.h>

// x (256,160,160) f32 -> out (256,320,640) f32
#define CH  256
#define H_  160
#define W0_ 160
#define RH  160
#define RW  320
#define OH  320
#define OW  640

#define TKR 32              // res rows per block
#define TKC 32              // res cols per block
#define NBX 10              // grid x blocks
#define NBY 5               // grid y blocks
// x tile: rows k0-2..k0+33 (36), cols m0-1..m0+16 (18). Stride 20 words ->
// wave read pattern = 2 lanes/bank (free).
#define XT_H 36
#define XT_W 18
#define XT_S 20

__global__ __launch_bounds__(256)
void upsample_tsd_conv_kernel(const float* __restrict__ x, float* __restrict__ out) {
    __shared__ float xs[XT_H][XT_S];

    const int c  = blockIdx.z;
    const int by = blockIdx.y, bx = blockIdx.x;
    const int k0 = by * TKR;
    const int j0 = bx * TKC;
    const int m0 = j0 >> 1;
    const float* __restrict__ xc = x + (size_t)c * (H_ * W0_);
    const int tid = threadIdx.x;

    // ---- Phase 1: stage raw x tile (index-clamped) -- <=3 loads/thread ----
    #pragma unroll
    for (int it = 0; it < 3; ++it) {
        int idx = tid + it * 256;
        if (idx < XT_H * XT_W) {
            int rr = idx / XT_W;
            int cc = idx - rr * XT_W;
            int gr = min(H_ - 1, max(0, k0 - 2 + rr));
            int gc = min(W0_ - 1, max(0, m0 - 1 + cc));
            xs[rr][cc] = xc[gr * W0_ + gc];
        }
    }
    __syncthreads();

    float* __restrict__ outc = out + (size_t)c * (OH * OW);

    // ---- Phase 2: res triple (rows k-1,k,k+1 x cols jc-1..jc+2) in regs,
    //      then bilinear 2x (.25/.75) + LR flip, 2 x float4 stores ----
    // t=0 handles even res rows (k even), t=1 odd: parity is compile-time.
    #pragma unroll
    for (int t = 0; t < 2; ++t) {
        const int kr = 2 * (tid >> 4) + t;     // local res row (parity == t)
        const int kc = (tid & 15) << 1;        // local res col (even)
        const int ml = (tid & 15) + 1;         // LDS col of x col m = (j0+kc)/2
        const int k  = k0 + kr;
        const int jc = j0 + kc;

        float rt0[4], rt1[4], rt2[4];          // res rows k-1, k, k+1

        if (t == 0) {   // k even: rows k+-1 odd (data at odd cols), row k even
            float X01 = xs[kr    ][ml],     X02 = xs[kr    ][ml + 1];
            float X10 = xs[kr + 1][ml - 1], X11 = xs[kr + 1][ml], X12 = xs[kr + 1][ml + 1];
            float X20 = xs[kr + 2][ml - 1], X21 = xs[kr + 2][ml], X22 = xs[kr + 2][ml + 1];
            float X30 = xs[kr + 3][ml - 1], X31 = xs[kr + 3][ml], X32 = xs[kr + 3][ml + 1];
            float X41 = xs[kr + 4][ml],     X42 = xs[kr + 4][ml + 1];
            rt0[0] = X10;
            rt0[1] = 0.25f * (X01 + X21 + X10 + X11);
            rt0[2] = X11;
            rt0[3] = 0.25f * (X02 + X22 + X11 + X12);
            rt1[0] = 0.25f * (X10 + X30 + X20 + X21);
            rt1[1] = X21;
            rt1[2] = 0.25f * (X11 + X31 + X21 + X22);
            rt1[3] = X22;
            rt2[0] = X30;
            rt2[1] = 0.25f * (X21 + X41 + X30 + X31);
            rt2[2] = X31;
            rt2[3] = 0.25f * (X22 + X42 + X31 + X32);
            // --- edge fixes (ordered: row-hole fixes, col fixes, row-clamp copy) ---
            if (by == 0 && kr == 0) {            // k==0: row-0 holes use row-reflect
                rt1[0] = 0.25f * (2.f * X30 + X20 + X21);
                rt1[2] = 0.25f * (2.f * X31 + X21 + X22);
            }
            if (by == NBY - 1 && kr == 30) {     // row 159 holes (even cols) are zero
                rt2[1] = 0.f; rt2[3] = 0.f;
            }
            if (bx == 0 && kc == 0) {            // res col -1 -> col 0
                rt0[0] = 0.25f * (X01 + X21 + 2.f * X11);   // hole(k-1,0) reflect
                rt1[0] = X21;                                // data(k,0)
                rt2[0] = (by == NBY - 1 && kr == 30) ? 0.f   // res(159,0) zero-hole
                         : 0.25f * (X21 + X41 + 2.f * X31); // hole(k+1,0) reflect
            }
            if (bx == NBX - 1 && kc == 30) {     // jc==318: col 319 + col 320->319
                rt1[2] = 0.f;                    // res(k,319) zero-hole
                rt0[3] = X11;                    // res(k-1,319) data = x[k-1,159]
                rt1[3] = 0.f;                    // res(k,320->319) zero-hole
                rt2[3] = X31;                    // res(k+1,319) data (also at row 159)
            }
            if (by == 0 && kr == 0) {            // res row -1 -> row 0 (last)
                rt0[0] = rt1[0]; rt0[1] = rt1[1]; rt0[2] = rt1[2]; rt0[3] = rt1[3];
            }
        } else {        // k odd: rows k+-1 even (data at even cols), row k odd
            float X00 = xs[kr    ][ml - 1], X01 = xs[kr    ][ml];
            float X10 = xs[kr + 1][ml - 1], X11 = xs[kr + 1][ml], X12 = xs[kr + 1][ml + 1];
            float X20 = xs[kr + 2][ml - 1], X21 = xs[kr + 2][ml], X22 = xs[kr + 2][ml + 1];
            float X30 = xs[kr + 3][ml - 1], X31 = xs[kr + 3][ml], X32 = xs[kr + 3][ml + 1];
            float X40 = xs[kr + 4][ml - 1], X41 = xs[kr + 4][ml];
            rt0[0] = 0.25f * (X00 + X20 + X10 + X11);
            rt0[1] = X11;
            rt0[2] = 0.25f * (X01 + X21 + X11 + X12);
            rt0[3] = X12;
            rt1[0] = X20;
            rt1[1] = 0.25f * (X11 + X31 + X20 + X21);
            rt1[2] = X21;
            rt1[3] = 0.25f * (X12 + X32 + X21 + X22);
            rt2[0] = 0.25f * (X20 + X40 + X30 + X31);
            rt2[1] = X31;
            rt2[2] = 0.25f * (X21 + X41 + X31 + X32);
            rt2[3] = X32;
            // --- edge fixes ---
            if (by == 0 && kr == 1) {            // k==1: row 0 (k-1) holes row-reflect
                rt0[0] = 0.25f * (2.f * X20 + X10 + X11);
                rt0[2] = 0.25f * (2.f * X21 + X11 + X12);
            }
            if (by == NBY - 1 && kr == 31) {     // k==159: own-row holes (even cols) zero
                rt1[1] = 0.f; rt1[3] = 0.f;
            }
            if (bx == 0 && kc == 0) {            // res col -1 -> col 0
                rt0[0] = X11;                                // data(k-1,0)
                rt1[0] = (by == NBY - 1 && kr == 31) ? 0.f   // res(159,0) zero-hole
                         : 0.25f * (X11 + X31 + 2.f * X21); // hole(k,0) reflect
                rt2[0] = X31;                                // data(k+1,0)
            }
            if (bx == NBX - 1 && kc == 30) {     // jc==318
                rt0[2] = 0.f;                    // res(k-1,319) zero-hole
                rt2[2] = 0.f;                    // res(k+1,319) zero-hole
                rt0[3] = 0.f;                    // res(k-1,320->319) zero-hole
                rt1[3] = X21;                    // res(k,319) data = x[k,159]
                rt2[3] = 0.f;                    // res(k+1,320->319) zero-hole
            }
            if (by == NBY - 1 && kr == 31) {     // res row 160 -> 159 (last)
                rt2[0] = rt1[0]; rt2[1] = rt1[1]; rt2[2] = rt1[2]; rt2[3] = rt1[3];
            }
        }

        // vertical blends: out row 2k <- (k-1,k) w (.25,.75); 2k+1 <- (k,k+1) w (.75,.25)
        float v00 = 0.25f * rt0[0] + 0.75f * rt1[0];
        float v01 = 0.25f * rt0[1] + 0.75f * rt1[1];
        float v02 = 0.25f * rt0[2] + 0.75f * rt1[2];
        float v03 = 0.25f * rt0[3] + 0.75f * rt1[3];
        float v10 = 0.75f * rt1[0] + 0.25f * rt2[0];
        float v11 = 0.75f * rt1[1] + 0.25f * rt2[1];
        float v12 = 0.75f * rt1[2] + 0.25f * rt2[2];
        float v13 = 0.75f * rt1[3] + 0.25f * rt2[3];
        // horizontal blends -> pre-flip cols 2jc..2jc+3
        float p0 = 0.25f * v00 + 0.75f * v01;
        float p1 = 0.75f * v01 + 0.25f * v02;
        float p2 = 0.25f * v01 + 0.75f * v02;
        float p3 = 0.75f * v02 + 0.25f * v03;
        float q0 = 0.25f * v10 + 0.75f * v11;
        float q1 = 0.75f * v11 + 0.25f * v12;
        float q2 = 0.25f * v11 + 0.75f * v12;
        float q3 = 0.75f * v12 + 0.25f * v13;

        const int oy  = 2 * k;
        const int oxf = OW - 4 - 2 * jc;       // flipped base col, 16B aligned
        // final[oxf+i] = pre[2jc+3-i]
        *reinterpret_cast<float4*>(&outc[(size_t)oy       * OW + oxf]) = make_float4(p3, p2, p1, p0);
        *reinterpret_cast<float4*>(&outc[(size_t)(oy + 1) * OW + oxf]) = make_float4(q3, q2, q1, q0);
    }
}

extern "C" void kernel_launch(void* const* d_in, const int* in_sizes, int n_in,
                              void* d_out, int out_size, void* d_ws, size_t ws_size,
                              hipStream_t stream) {
    (void)in_sizes; (void)n_in; (void)d_ws; (void)ws_size; (void)out_size;
    const float* x = (const float*)d_in[0];
    float* out = (float*)d_out;
    dim3 grid(NBX, NBY, CH);   // (10, 5, 256)
    dim3 block(256);
    upsample_tsd_conv_kernel<<<grid, block, 0, stream>>>(x, out);
}

// Round 5
// 49.433 us; speedup vs baseline: 1.1039x; 1.0293x over previous
//
#include <hip/hip_runtime.h>

// x (256,160,160) f32 -> out (256,320,640) f32
#define CH  256
#define H_  160
#define W0_ 160
#define RH  160
#define RW  320
#define OH  320
#define OW  640

#define TKR 8               // res rows per block
#define TKC 64              // res cols per block
#define NBX 5               // 320/64
#define NBY 20              // 160/8
// x tile: rows k0-2..k0+9 (12), cols m0-1..m0+32 (34); stride 36 words
#define XT_H 12
#define XT_W 34
#define XT_S 36

typedef float f4 __attribute__((ext_vector_type(4)));

__global__ __launch_bounds__(256)
void upsample_tsd_conv_kernel(const float* __restrict__ x, float* __restrict__ out) {
    __shared__ float xs[XT_H][XT_S];

    const int c  = blockIdx.z;
    const int by = blockIdx.y, bx = blockIdx.x;
    const int k0 = by * TKR;
    const int j0 = bx * TKC;
    const int m0 = j0 >> 1;
    const float* __restrict__ xc = x + (size_t)c * (H_ * W0_);
    const int tid = threadIdx.x;

    // ---- Phase 1: stage raw x tile (index-clamped), 408 elems, <=2 loads ----
    #pragma unroll
    for (int it = 0; it < 2; ++it) {
        int idx = tid + it * 256;
        if (idx < XT_H * XT_W) {
            int rr = idx / XT_W;
            int cc = idx - rr * XT_W;
            int gr = min(H_ - 1, max(0, k0 - 2 + rr));
            int gc = min(W0_ - 1, max(0, m0 - 1 + cc));
            xs[rr][cc] = xc[gr * W0_ + gc];
        }
    }
    __syncthreads();

    float* __restrict__ outc = out + (size_t)c * (OH * OW);

    // ---- Phase 2: one 3x4 res patch -> 2x4 outputs per thread ----
    // Wave-uniform parity: wave0 rows {0,2}, wave1 {4,6}, wave2 {1,3}, wave3 {5,7}
    const int par = tid >> 7;                                  // wave-uniform
    const int kr  = ((tid >> 6) & 1) * 4 + ((tid >> 5) & 1) * 2 + par;
    const int cp  = tid & 31;          // col-pair index: res cols 2cp, 2cp+1
    const int ml  = cp + 1;            // LDS col of x col m0+cp
    const int k   = k0 + kr;
    const int jc  = j0 + (cp << 1);

    float rt0[4], rt1[4], rt2[4];      // res rows k-1, k, k+1 x cols jc-1..jc+2

    if (par == 0) {   // k even: rows k+-1 odd (data at odd cols), row k even
        float X01 = xs[kr    ][ml],     X02 = xs[kr    ][ml + 1];
        float X10 = xs[kr + 1][ml - 1], X11 = xs[kr + 1][ml], X12 = xs[kr + 1][ml + 1];
        float X20 = xs[kr + 2][ml - 1], X21 = xs[kr + 2][ml], X22 = xs[kr + 2][ml + 1];
        float X30 = xs[kr + 3][ml - 1], X31 = xs[kr + 3][ml], X32 = xs[kr + 3][ml + 1];
        float X41 = xs[kr + 4][ml],     X42 = xs[kr + 4][ml + 1];
        rt0[0] = X10;
        rt0[1] = 0.25f * (X01 + X21 + X10 + X11);
        rt0[2] = X11;
        rt0[3] = 0.25f * (X02 + X22 + X11 + X12);
        rt1[0] = 0.25f * (X10 + X30 + X20 + X21);
        rt1[1] = X21;
        rt1[2] = 0.25f * (X11 + X31 + X21 + X22);
        rt1[3] = X22;
        rt2[0] = X30;
        rt2[1] = 0.25f * (X21 + X41 + X30 + X31);
        rt2[2] = X31;
        rt2[3] = 0.25f * (X22 + X42 + X31 + X32);
        if (by == 0 && kr == 0) {              // k==0: row-0 holes row-reflect
            rt1[0] = 0.25f * (2.f * X30 + X20 + X21);
            rt1[2] = 0.25f * (2.f * X31 + X21 + X22);
        }
        if (by == NBY - 1 && kr == TKR - 2) {  // row 159 holes (even cols) zero
            rt2[1] = 0.f; rt2[3] = 0.f;
        }
        if (bx == 0 && cp == 0) {              // res col -1 -> col 0
            rt0[0] = 0.25f * (X01 + X21 + 2.f * X11);
            rt1[0] = X21;
            rt2[0] = (by == NBY - 1 && kr == TKR - 2) ? 0.f
                     : 0.25f * (X21 + X41 + 2.f * X31);
        }
        if (bx == NBX - 1 && cp == 31) {       // jc==318: col 319 + col 320->319
            rt1[2] = 0.f;
            rt0[3] = X11;
            rt1[3] = 0.f;
            rt2[3] = X31;
        }
        if (by == 0 && kr == 0) {              // res row -1 -> row 0
            rt0[0] = rt1[0]; rt0[1] = rt1[1]; rt0[2] = rt1[2]; rt0[3] = rt1[3];
        }
    } else {          // k odd: rows k+-1 even (data at even cols), row k odd
        float X00 = xs[kr    ][ml - 1], X01 = xs[kr    ][ml];
        float X10 = xs[kr + 1][ml - 1], X11 = xs[kr + 1][ml], X12 = xs[kr + 1][ml + 1];
        float X20 = xs[kr + 2][ml - 1], X21 = xs[kr + 2][ml], X22 = xs[kr + 2][ml + 1];
        float X30 = xs[kr + 3][ml - 1], X31 = xs[kr + 3][ml], X32 = xs[kr + 3][ml + 1];
        float X40 = xs[kr + 4][ml - 1], X41 = xs[kr + 4][ml];
        rt0[0] = 0.25f * (X00 + X20 + X10 + X11);
        rt0[1] = X11;
        rt0[2] = 0.25f * (X01 + X21 + X11 + X12);
        rt0[3] = X12;
        rt1[0] = X20;
        rt1[1] = 0.25f * (X11 + X31 + X20 + X21);
        rt1[2] = X21;
        rt1[3] = 0.25f * (X12 + X32 + X21 + X22);
        rt2[0] = 0.25f * (X20 + X40 + X30 + X31);
        rt2[1] = X31;
        rt2[2] = 0.25f * (X21 + X41 + X31 + X32);
        rt2[3] = X32;
        if (by == 0 && kr == 1) {              // k==1: row 0 holes row-reflect
            rt0[0] = 0.25f * (2.f * X20 + X10 + X11);
            rt0[2] = 0.25f * (2.f * X21 + X11 + X12);
        }
        if (by == NBY - 1 && kr == TKR - 1) {  // k==159: own-row holes zero
            rt1[1] = 0.f; rt1[3] = 0.f;
        }
        if (bx == 0 && cp == 0) {              // res col -1 -> col 0
            rt0[0] = X11;
            rt1[0] = (by == NBY - 1 && kr == TKR - 1) ? 0.f
                     : 0.25f * (X11 + X31 + 2.f * X21);
            rt2[0] = X31;
        }
        if (bx == NBX - 1 && cp == 31) {       // jc==318
            rt0[2] = 0.f; rt2[2] = 0.f;
            rt0[3] = 0.f;
            rt1[3] = X21;
            rt2[3] = 0.f;
        }
        if (by == NBY - 1 && kr == TKR - 1) {  // res row 160 -> 159
            rt2[0] = rt1[0]; rt2[1] = rt1[1]; rt2[2] = rt1[2]; rt2[3] = rt1[3];
        }
    }

    // vertical blends: out row 2k <- (k-1,k) w (.25,.75); 2k+1 <- (k,k+1) w (.75,.25)
    float v00 = 0.25f * rt0[0] + 0.75f * rt1[0];
    float v01 = 0.25f * rt0[1] + 0.75f * rt1[1];
    float v02 = 0.25f * rt0[2] + 0.75f * rt1[2];
    float v03 = 0.25f * rt0[3] + 0.75f * rt1[3];
    float v10 = 0.75f * rt1[0] + 0.25f * rt2[0];
    float v11 = 0.75f * rt1[1] + 0.25f * rt2[1];
    float v12 = 0.75f * rt1[2] + 0.25f * rt2[2];
    float v13 = 0.75f * rt1[3] + 0.25f * rt2[3];
    // horizontal blends -> pre-flip cols 2jc..2jc+3
    float p0 = 0.25f * v00 + 0.75f * v01;
    float p1 = 0.75f * v01 + 0.25f * v02;
    float p2 = 0.25f * v01 + 0.75f * v02;
    float p3 = 0.75f * v02 + 0.25f * v03;
    float q0 = 0.25f * v10 + 0.75f * v11;
    float q1 = 0.75f * v11 + 0.25f * v12;
    float q2 = 0.25f * v11 + 0.75f * v12;
    float q3 = 0.75f * v12 + 0.25f * v13;

    const int oy  = 2 * k;
    const int oxf = OW - 4 - 2 * jc;   // flipped base col; half-wave = 512B contig
    f4 s0; s0.x = p3; s0.y = p2; s0.z = p1; s0.w = p0;
    f4 s1; s1.x = q3; s1.y = q2; s1.z = q1; s1.w = q0;
    __builtin_nontemporal_store(s0, reinterpret_cast<f4*>(&outc[(size_t)oy       * OW + oxf]));
    __builtin_nontemporal_store(s1, reinterpret_cast<f4*>(&outc[(size_t)(oy + 1) * OW + oxf]));
}

extern "C" void kernel_launch(void* const* d_in, const int* in_sizes, int n_in,
                              void* d_out, int out_size, void* d_ws, size_t ws_size,
                              hipStream_t stream) {
    (void)in_sizes; (void)n_in; (void)d_ws; (void)ws_size; (void)out_size;
    const float* x = (const float*)d_in[0];
    float* out = (float*)d_out;
    dim3 grid(NBX, NBY, CH);   // (5, 20, 256)
    dim3 block(256);
    upsample_tsd_conv_kernel<<<grid, block, 0, stream>>>(x, out);
}

// Round 6
// 40.159 us; speedup vs baseline: 1.3588x; 1.2309x over previous
//
#include <hip/hip_runtime.h>

// x (256,160,160) f32 -> out (256,320,640) f32
#define CH  256
#define H_  160
#define W0_ 160
#define RH  160
#define RW  320
#define OH  320
#define OW  640

#define TKR 8               // res rows per block
#define TKC 64              // res cols per block
#define NBX 5               // 320/64
#define NBY 20              // 160/8
#define NWG (NBX * NBY * CH)        // 25600
#define NXCD 8
#define CPX (NWG / NXCD)            // 3200 blocks per XCD chunk
// x tile: rows k0-2..k0+9 (12), cols m0-1..m0+32 (34); stride 36 words
#define XT_H 12
#define XT_W 34
#define XT_S 36

typedef float f4 __attribute__((ext_vector_type(4)));

__global__ __launch_bounds__(256)
void upsample_tsd_conv_kernel(const float* __restrict__ x, float* __restrict__ out) {
    __shared__ float xs[XT_H][XT_S];

    // XCD-chunk swizzle (bijective, NWG % 8 == 0): XCD k owns original blocks
    // [k*3200,(k+1)*3200) = 32 complete channels -> each x-slab lives in ONE L2.
    const int bid  = blockIdx.x;
    const int orig = (bid & (NXCD - 1)) * CPX + (bid >> 3);
    const int c    = orig / (NBX * NBY);        // channel-major
    const int tsub = orig - c * (NBX * NBY);
    const int by   = tsub / NBX;
    const int bx   = tsub - by * NBX;

    const int k0 = by * TKR;
    const int j0 = bx * TKC;
    const int m0 = j0 >> 1;
    const float* __restrict__ xc = x + (size_t)c * (H_ * W0_);
    const int tid = threadIdx.x;

    // ---- Phase 1: stage raw x tile (index-clamped), 408 elems, <=2 loads ----
    #pragma unroll
    for (int it = 0; it < 2; ++it) {
        int idx = tid + it * 256;
        if (idx < XT_H * XT_W) {
            int rr = idx / XT_W;
            int cc = idx - rr * XT_W;
            int gr = min(H_ - 1, max(0, k0 - 2 + rr));
            int gc = min(W0_ - 1, max(0, m0 - 1 + cc));
            xs[rr][cc] = xc[gr * W0_ + gc];
        }
    }
    __syncthreads();

    float* __restrict__ outc = out + (size_t)c * (OH * OW);

    // ---- Phase 2: one 3x4 res patch -> 2x4 outputs per thread ----
    // Wave-uniform parity: wave0 rows {0,2}, wave1 {4,6}, wave2 {1,3}, wave3 {5,7}
    const int par = tid >> 7;                                  // wave-uniform
    const int kr  = ((tid >> 6) & 1) * 4 + ((tid >> 5) & 1) * 2 + par;
    const int cp  = tid & 31;          // col-pair index: res cols 2cp, 2cp+1
    const int ml  = cp + 1;            // LDS col of x col m0+cp
    const int k   = k0 + kr;
    const int jc  = j0 + (cp << 1);

    float rt0[4], rt1[4], rt2[4];      // res rows k-1, k, k+1 x cols jc-1..jc+2

    if (par == 0) {   // k even: rows k+-1 odd (data at odd cols), row k even
        float X01 = xs[kr    ][ml],     X02 = xs[kr    ][ml + 1];
        float X10 = xs[kr + 1][ml - 1], X11 = xs[kr + 1][ml], X12 = xs[kr + 1][ml + 1];
        float X20 = xs[kr + 2][ml - 1], X21 = xs[kr + 2][ml], X22 = xs[kr + 2][ml + 1];
        float X30 = xs[kr + 3][ml - 1], X31 = xs[kr + 3][ml], X32 = xs[kr + 3][ml + 1];
        float X41 = xs[kr + 4][ml],     X42 = xs[kr + 4][ml + 1];
        rt0[0] = X10;
        rt0[1] = 0.25f * (X01 + X21 + X10 + X11);
        rt0[2] = X11;
        rt0[3] = 0.25f * (X02 + X22 + X11 + X12);
        rt1[0] = 0.25f * (X10 + X30 + X20 + X21);
        rt1[1] = X21;
        rt1[2] = 0.25f * (X11 + X31 + X21 + X22);
        rt1[3] = X22;
        rt2[0] = X30;
        rt2[1] = 0.25f * (X21 + X41 + X30 + X31);
        rt2[2] = X31;
        rt2[3] = 0.25f * (X22 + X42 + X31 + X32);
        if (by == 0 && kr == 0) {              // k==0: row-0 holes row-reflect
            rt1[0] = 0.25f * (2.f * X30 + X20 + X21);
            rt1[2] = 0.25f * (2.f * X31 + X21 + X22);
        }
        if (by == NBY - 1 && kr == TKR - 2) {  // row 159 holes (even cols) zero
            rt2[1] = 0.f; rt2[3] = 0.f;
        }
        if (bx == 0 && cp == 0) {              // res col -1 -> col 0
            rt0[0] = 0.25f * (X01 + X21 + 2.f * X11);
            rt1[0] = X21;
            rt2[0] = (by == NBY - 1 && kr == TKR - 2) ? 0.f
                     : 0.25f * (X21 + X41 + 2.f * X31);
        }
        if (bx == NBX - 1 && cp == 31) {       // jc==318: col 319 + col 320->319
            rt1[2] = 0.f;
            rt0[3] = X11;
            rt1[3] = 0.f;
            rt2[3] = X31;
        }
        if (by == 0 && kr == 0) {              // res row -1 -> row 0
            rt0[0] = rt1[0]; rt0[1] = rt1[1]; rt0[2] = rt1[2]; rt0[3] = rt1[3];
        }
    } else {          // k odd: rows k+-1 even (data at even cols), row k odd
        float X00 = xs[kr    ][ml - 1], X01 = xs[kr    ][ml];
        float X10 = xs[kr + 1][ml - 1], X11 = xs[kr + 1][ml], X12 = xs[kr + 1][ml + 1];
        float X20 = xs[kr + 2][ml - 1], X21 = xs[kr + 2][ml], X22 = xs[kr + 2][ml + 1];
        float X30 = xs[kr + 3][ml - 1], X31 = xs[kr + 3][ml], X32 = xs[kr + 3][ml + 1];
        float X40 = xs[kr + 4][ml - 1], X41 = xs[kr + 4][ml];
        rt0[0] = 0.25f * (X00 + X20 + X10 + X11);
        rt0[1] = X11;
        rt0[2] = 0.25f * (X01 + X21 + X11 + X12);
        rt0[3] = X12;
        rt1[0] = X20;
        rt1[1] = 0.25f * (X11 + X31 + X20 + X21);
        rt1[2] = X21;
        rt1[3] = 0.25f * (X12 + X32 + X21 + X22);
        rt2[0] = 0.25f * (X20 + X40 + X30 + X31);
        rt2[1] = X31;
        rt2[2] = 0.25f * (X21 + X41 + X31 + X32);
        rt2[3] = X32;
        if (by == 0 && kr == 1) {              // k==1: row 0 holes row-reflect
            rt0[0] = 0.25f * (2.f * X20 + X10 + X11);
            rt0[2] = 0.25f * (2.f * X21 + X11 + X12);
        }
        if (by == NBY - 1 && kr == TKR - 1) {  // k==159: own-row holes zero
            rt1[1] = 0.f; rt1[3] = 0.f;
        }
        if (bx == 0 && cp == 0) {              // res col -1 -> col 0
            rt0[0] = X11;
            rt1[0] = (by == NBY - 1 && kr == TKR - 1) ? 0.f
                     : 0.25f * (X11 + X31 + 2.f * X21);
            rt2[0] = X31;
        }
        if (bx == NBX - 1 && cp == 31) {       // jc==318
            rt0[2] = 0.f; rt2[2] = 0.f;
            rt0[3] = 0.f;
            rt1[3] = X21;
            rt2[3] = 0.f;
        }
        if (by == NBY - 1 && kr == TKR - 1) {  // res row 160 -> 159
            rt2[0] = rt1[0]; rt2[1] = rt1[1]; rt2[2] = rt1[2]; rt2[3] = rt1[3];
        }
    }

    // vertical blends: out row 2k <- (k-1,k) w (.25,.75); 2k+1 <- (k,k+1) w (.75,.25)
    float v00 = 0.25f * rt0[0] + 0.75f * rt1[0];
    float v01 = 0.25f * rt0[1] + 0.75f * rt1[1];
    float v02 = 0.25f * rt0[2] + 0.75f * rt1[2];
    float v03 = 0.25f * rt0[3] + 0.75f * rt1[3];
    float v10 = 0.75f * rt1[0] + 0.25f * rt2[0];
    float v11 = 0.75f * rt1[1] + 0.25f * rt2[1];
    float v12 = 0.75f * rt1[2] + 0.25f * rt2[2];
    float v13 = 0.75f * rt1[3] + 0.25f * rt2[3];
    // horizontal blends -> pre-flip cols 2jc..2jc+3
    float p0 = 0.25f * v00 + 0.75f * v01;
    float p1 = 0.75f * v01 + 0.25f * v02;
    float p2 = 0.25f * v01 + 0.75f * v02;
    float p3 = 0.75f * v02 + 0.25f * v03;
    float q0 = 0.25f * v10 + 0.75f * v11;
    float q1 = 0.75f * v11 + 0.25f * v12;
    float q2 = 0.25f * v11 + 0.75f * v12;
    float q3 = 0.75f * v12 + 0.25f * v13;

    const int oy  = 2 * k;
    const int oxf = OW - 4 - 2 * jc;   // flipped base col; half-wave = 512B contig
    f4 s0; s0.x = p3; s0.y = p2; s0.z = p1; s0.w = p0;
    f4 s1; s1.x = q3; s1.y = q2; s1.z = q1; s1.w = q0;
    __builtin_nontemporal_store(s0, reinterpret_cast<f4*>(&outc[(size_t)oy       * OW + oxf]));
    __builtin_nontemporal_store(s1, reinterpret_cast<f4*>(&outc[(size_t)(oy + 1) * OW + oxf]));
}

extern "C" void kernel_launch(void* const* d_in, const int* in_sizes, int n_in,
                              void* d_out, int out_size, void* d_ws, size_t ws_size,
                              hipStream_t stream) {
    (void)in_sizes; (void)n_in; (void)d_ws; (void)ws_size; (void)out_size;
    const float* x = (const float*)d_in[0];
    float* out = (float*)d_out;
    dim3 grid(NWG);            // 25600 blocks, 1D, XCD-chunk swizzled in-kernel
    dim3 block(256);
    upsample_tsd_conv_kernel<<<grid, block, 0, stream>>>(x, out);
}

// Round 7
// 39.393 us; speedup vs baseline: 1.3852x; 1.0194x over previous
//
#include <hip/hip_runtime.h>

// x (256,160,160) f32 -> out (256,320,640) f32
#define CH  256
#define H_  160
#define W0_ 160
#define RH  160
#define RW  320
#define OH  320
#define OW  640

#define TKR 8               // res rows per block
#define TKC 64              // res cols per block
#define NBX 5               // 320/64
#define NBY 20              // 160/8
#define NWG (NBX * NBY * CH)        // 25600
#define NXCD 8
#define CPX (NWG / NXCD)            // 3200 blocks per XCD chunk
// x tile: rows k0-2..k0+9 (12), cols m0-1..m0+32 (34); stride 36 words
#define XT_H 12
#define XT_W 34
#define XT_S 36

typedef float f4 __attribute__((ext_vector_type(4)));

__global__ __launch_bounds__(256)
void upsample_tsd_conv_kernel(const float* __restrict__ x, float* __restrict__ out) {
    __shared__ float xs[XT_H][XT_S];

    // XCD-chunk swizzle (bijective, NWG % 8 == 0): XCD k owns original blocks
    // [k*3200,(k+1)*3200) = 32 complete channels -> each x-slab lives in ONE L2.
    const int bid  = blockIdx.x;
    const int orig = (bid & (NXCD - 1)) * CPX + (bid >> 3);
    const int c    = orig / (NBX * NBY);        // channel-major
    const int tsub = orig - c * (NBX * NBY);
    const int by   = tsub / NBX;
    const int bx   = tsub - by * NBX;

    const int k0 = by * TKR;
    const int j0 = bx * TKC;
    const int m0 = j0 >> 1;
    const float* __restrict__ xc = x + (size_t)c * (H_ * W0_);
    const int tid = threadIdx.x;

    // ---- Phase 1: stage raw x tile (index-clamped), 408 elems, <=2 loads ----
    #pragma unroll
    for (int it = 0; it < 2; ++it) {
        int idx = tid + it * 256;
        if (idx < XT_H * XT_W) {
            int rr = idx / XT_W;
            int cc = idx - rr * XT_W;
            int gr = min(H_ - 1, max(0, k0 - 2 + rr));
            int gc = min(W0_ - 1, max(0, m0 - 1 + cc));
            xs[rr][cc] = xc[gr * W0_ + gc];
        }
    }
    __syncthreads();

    float* __restrict__ outc = out + (size_t)c * (OH * OW);

    // ---- Phase 2: one 3x4 res patch -> 2x4 outputs per thread ----
    // Wave-uniform parity: wave0 rows {0,2}, wave1 {4,6}, wave2 {1,3}, wave3 {5,7}
    const int par = tid >> 7;                                  // wave-uniform
    const int kr  = ((tid >> 6) & 1) * 4 + ((tid >> 5) & 1) * 2 + par;
    const int cp  = tid & 31;          // col-pair index: res cols 2cp, 2cp+1
    const int ml  = cp + 1;            // LDS col of x col m0+cp
    const int k   = k0 + kr;
    const int jc  = j0 + (cp << 1);

    float rt0[4], rt1[4], rt2[4];      // res rows k-1, k, k+1 x cols jc-1..jc+2

    if (par == 0) {   // k even: rows k+-1 odd (data at odd cols), row k even
        float X01 = xs[kr    ][ml],     X02 = xs[kr    ][ml + 1];
        float X10 = xs[kr + 1][ml - 1], X11 = xs[kr + 1][ml], X12 = xs[kr + 1][ml + 1];
        float X20 = xs[kr + 2][ml - 1], X21 = xs[kr + 2][ml], X22 = xs[kr + 2][ml + 1];
        float X30 = xs[kr + 3][ml - 1], X31 = xs[kr + 3][ml], X32 = xs[kr + 3][ml + 1];
        float X41 = xs[kr + 4][ml],     X42 = xs[kr + 4][ml + 1];
        rt0[0] = X10;
        rt0[1] = 0.25f * (X01 + X21 + X10 + X11);
        rt0[2] = X11;
        rt0[3] = 0.25f * (X02 + X22 + X11 + X12);
        rt1[0] = 0.25f * (X10 + X30 + X20 + X21);
        rt1[1] = X21;
        rt1[2] = 0.25f * (X11 + X31 + X21 + X22);
        rt1[3] = X22;
        rt2[0] = X30;
        rt2[1] = 0.25f * (X21 + X41 + X30 + X31);
        rt2[2] = X31;
        rt2[3] = 0.25f * (X22 + X42 + X31 + X32);
        if (by == 0 && kr == 0) {              // k==0: row-0 holes row-reflect
            rt1[0] = 0.25f * (2.f * X30 + X20 + X21);
            rt1[2] = 0.25f * (2.f * X31 + X21 + X22);
        }
        if (by == NBY - 1 && kr == TKR - 2) {  // row 159 holes (even cols) zero
            rt2[1] = 0.f; rt2[3] = 0.f;
        }
        if (bx == 0 && cp == 0) {              // res col -1 -> col 0
            rt0[0] = 0.25f * (X01 + X21 + 2.f * X11);
            rt1[0] = X21;
            rt2[0] = (by == NBY - 1 && kr == TKR - 2) ? 0.f
                     : 0.25f * (X21 + X41 + 2.f * X31);
        }
        if (bx == NBX - 1 && cp == 31) {       // jc==318: col 319 + col 320->319
            rt1[2] = 0.f;
            rt0[3] = X11;
            rt1[3] = 0.f;
            rt2[3] = X31;
        }
        if (by == 0 && kr == 0) {              // res row -1 -> row 0
            rt0[0] = rt1[0]; rt0[1] = rt1[1]; rt0[2] = rt1[2]; rt0[3] = rt1[3];
        }
    } else {          // k odd: rows k+-1 even (data at even cols), row k odd
        float X00 = xs[kr    ][ml - 1], X01 = xs[kr    ][ml];
        float X10 = xs[kr + 1][ml - 1], X11 = xs[kr + 1][ml], X12 = xs[kr + 1][ml + 1];
        float X20 = xs[kr + 2][ml - 1], X21 = xs[kr + 2][ml], X22 = xs[kr + 2][ml + 1];
        float X30 = xs[kr + 3][ml - 1], X31 = xs[kr + 3][ml], X32 = xs[kr + 3][ml + 1];
        float X40 = xs[kr + 4][ml - 1], X41 = xs[kr + 4][ml];
        rt0[0] = 0.25f * (X00 + X20 + X10 + X11);
        rt0[1] = X11;
        rt0[2] = 0.25f * (X01 + X21 + X11 + X12);
        rt0[3] = X12;
        rt1[0] = X20;
        rt1[1] = 0.25f * (X11 + X31 + X20 + X21);
        rt1[2] = X21;
        rt1[3] = 0.25f * (X12 + X32 + X21 + X22);
        rt2[0] = 0.25f * (X20 + X40 + X30 + X31);
        rt2[1] = X31;
        rt2[2] = 0.25f * (X21 + X41 + X31 + X32);
        rt2[3] = X32;
        if (by == 0 && kr == 1) {              // k==1: row 0 holes row-reflect
            rt0[0] = 0.25f * (2.f * X20 + X10 + X11);
            rt0[2] = 0.25f * (2.f * X21 + X11 + X12);
        }
        if (by == NBY - 1 && kr == TKR - 1) {  // k==159: own-row holes zero
            rt1[1] = 0.f; rt1[3] = 0.f;
        }
        if (bx == 0 && cp == 0) {              // res col -1 -> col 0
            rt0[0] = X11;
            rt1[0] = (by == NBY - 1 && kr == TKR - 1) ? 0.f
                     : 0.25f * (X11 + X31 + 2.f * X21);
            rt2[0] = X31;
        }
        if (bx == NBX - 1 && cp == 31) {       // jc==318
            rt0[2] = 0.f; rt2[2] = 0.f;
            rt0[3] = 0.f;
            rt1[3] = X21;
            rt2[3] = 0.f;
        }
        if (by == NBY - 1 && kr == TKR - 1) {  // res row 160 -> 159
            rt2[0] = rt1[0]; rt2[1] = rt1[1]; rt2[2] = rt1[2]; rt2[3] = rt1[3];
        }
    }

    // vertical blends: out row 2k <- (k-1,k) w (.25,.75); 2k+1 <- (k,k+1) w (.75,.25)
    float v00 = 0.25f * rt0[0] + 0.75f * rt1[0];
    float v01 = 0.25f * rt0[1] + 0.75f * rt1[1];
    float v02 = 0.25f * rt0[2] + 0.75f * rt1[2];
    float v03 = 0.25f * rt0[3] + 0.75f * rt1[3];
    float v10 = 0.75f * rt1[0] + 0.25f * rt2[0];
    float v11 = 0.75f * rt1[1] + 0.25f * rt2[1];
    float v12 = 0.75f * rt1[2] + 0.25f * rt2[2];
    float v13 = 0.75f * rt1[3] + 0.25f * rt2[3];
    // horizontal blends -> pre-flip cols 2jc..2jc+3
    float p0 = 0.25f * v00 + 0.75f * v01;
    float p1 = 0.75f * v01 + 0.25f * v02;
    float p2 = 0.25f * v01 + 0.75f * v02;
    float p3 = 0.75f * v02 + 0.25f * v03;
    float q0 = 0.25f * v10 + 0.75f * v11;
    float q1 = 0.75f * v11 + 0.25f * v12;
    float q2 = 0.25f * v11 + 0.75f * v12;
    float q3 = 0.75f * v12 + 0.25f * v13;

    const int oy  = 2 * k;
    const int oxf = OW - 4 - 2 * jc;   // flipped base col; half-wave = 512B contig
    // A/B vs R6: plain (L2-cached) stores instead of nontemporal — single lever.
    *reinterpret_cast<f4*>(&outc[(size_t)oy       * OW + oxf]) = f4{p3, p2, p1, p0};
    *reinterpret_cast<f4*>(&outc[(size_t)(oy + 1) * OW + oxf]) = f4{q3, q2, q1, q0};
}

extern "C" void kernel_launch(void* const* d_in, const int* in_sizes, int n_in,
                              void* d_out, int out_size, void* d_ws, size_t ws_size,
                              hipStream_t stream) {
    (void)in_sizes; (void)n_in; (void)d_ws; (void)ws_size; (void)out_size;
    const float* x = (const float*)d_in[0];
    float* out = (float*)d_out;
    dim3 grid(NWG);            // 25600 blocks, 1D, XCD-chunk swizzled in-kernel
    dim3 block(256);
    upsample_tsd_conv_kernel<<<grid, block, 0, stream>>>(x, out);
}